// Round 24
// baseline (288.808 us; speedup 1.0000x reference)
//
#include <hip/hip_runtime.h>
#include <cstdint>
#include <cstddef>

#define B_    16
#define C_    256
#define HW_   64
#define N_    4096      // 64*64 spatial
#define K_    512
#define NROW_ 65536     // B_*N_

typedef __attribute__((ext_vector_type(8))) __bf16 bf16x8;
typedef __attribute__((ext_vector_type(4))) float floatx4;

struct P2 { float v1; int k1; float v2; int k2; };

__device__ __forceinline__ bool lexless(float v, int k, float bv, int bk) {
    return (v < bv) || (v == bv && k < bk);
}
__device__ __forceinline__ void ins2(float v, int k, float& v1, int& k1, float& v2, int& k2) {
    if (lexless(v, k, v1, k1)) { v2 = v1; k2 = k1; v1 = v; k1 = k; }
    else if (lexless(v, k, v2, k2)) { v2 = v; k2 = k; }
}
// 16-B record moves (force b128 / dwordx4)
__device__ __forceinline__ P2 ldP(const P2* p) {
    uint4 u = *(const uint4*)p;
    P2 r; r.v1 = __uint_as_float(u.x); r.k1 = (int)u.y;
    r.v2 = __uint_as_float(u.z); r.k2 = (int)u.w; return r;
}
__device__ __forceinline__ void stP(P2* p, float v1, int k1, float v2, int k2) {
    uint4 u; u.x = __float_as_uint(v1); u.y = (unsigned)k1;
    u.z = __float_as_uint(v2); u.w = (unsigned)k2;
    *(uint4*)p = u;
}
__device__ __forceinline__ void insP(P2 p, float& v1, int& k1, float& v2, int& k2) {
    ins2(p.v1, p.k1, v1, k1, v2, k2);
    ins2(p.v2, p.k2, v1, k1, v2, k2);
}

// Bpack layout: [ct 8][plane 2][cq 4][n 512][i 8] bf16, 512 KB.
// cand layout (row-contiguous): [row_slot 65536][j 32] P2, 32 MB.

// ---------------- kernel 1: codebook prep: e2 + packed bf16 hi/lo tiles -------
__global__ void prep_kernel(const float* __restrict__ cb, float* __restrict__ e2,
                            __bf16* __restrict__ Bpack, double* __restrict__ lossAcc) {
    int n = blockIdx.x, t = threadIdx.x;
    if (n == 0 && t == 0) *lossAcc = 0.0;
    float4 v = *(const float4*)(cb + (size_t)n * C_ + t * 4);
    float vv[4] = {v.x, v.y, v.z, v.w};
    __bf16 h[4], l[4];
    float s = 0.f;
    #pragma unroll
    for (int i = 0; i < 4; ++i) {
        h[i] = (__bf16)vv[i];
        l[i] = (__bf16)(vv[i] - (float)h[i]);
        s = fmaf(vv[i], vv[i], s);
    }
    int ct = t >> 3, cq = (t >> 1) & 3, i0 = (t & 1) * 4;
    size_t base = (size_t)ct * 32768;
    size_t off0 = base + ((size_t)(0 * 4 + cq) * 512 + n) * 8 + i0;   // hi plane
    size_t off1 = base + ((size_t)(1 * 4 + cq) * 512 + n) * 8 + i0;   // lo plane
    *(ushort4*)&Bpack[off0] = *(ushort4*)h;
    *(ushort4*)&Bpack[off1] = *(ushort4*)l;
    #pragma unroll
    for (int off = 32; off; off >>= 1) s += __shfl_down(s, off);
    if (t == 0) e2[n] = s;
}

// ---------------- kernel 2: SWAPPED-MFMA GEMM + per-thread top-2 (R21 best) ---
#define GLD(dst, voff, sbase, OFF) \
    asm volatile("global_load_dwordx4 %0, %1, %2 offset:" OFF \
                 : "=v"(dst) : "v"(voff), "s"(sbase))

__launch_bounds__(512, 4)
__global__ void main_kernel(const float* __restrict__ pq,
                            const __bf16* __restrict__ Bpack,
                            const float* __restrict__ e2, P2* __restrict__ cand,
                            float* __restrict__ x2) {
    const int Mtile = blockIdx.x;
    const int tid  = threadIdx.x;
    const int wave = tid >> 6, lane = tid & 63;
    const int lm = lane & 15, quad = lane >> 4;
    const int b  = Mtile >> 6;
    const int s0 = (Mtile * 64) & 4095;

    __shared__ __attribute__((aligned(16))) __bf16 Afull[2][64][260]; // 66.5 KB
    __shared__ float  xs[8][64];                                      // 2 KB

    floatx4 acc[4][4];
    #pragma unroll
    for (int i = 0; i < 4; ++i)
        #pragma unroll
        for (int j = 0; j < 4; ++j) acc[i][j] = (floatx4)0.f;

    // ---- prologue: 32 independent coalesced pq loads (measured ~2 us) ----
    const float* pqA = pq + (size_t)b * (C_ * N_) + s0 + lane;
    float af[8][4];
    #pragma unroll
    for (int ct = 0; ct < 8; ++ct)
        #pragma unroll
        for (int i = 0; i < 4; ++i)
            af[ct][i] = pqA[(size_t)(ct * 32 + wave * 4 + i) * N_];

    float x2loc = 0.f;
    #pragma unroll
    for (int ct = 0; ct < 8; ++ct) {
        __bf16 h[4], l[4];
        #pragma unroll
        for (int i = 0; i < 4; ++i) {
            float a = af[ct][i];
            h[i] = (__bf16)a;
            l[i] = (__bf16)(a - (float)h[i]);
            x2loc = fmaf(a, a, x2loc);
        }
        *(ushort4*)&Afull[0][lane][ct * 32 + wave * 4] = *(ushort4*)h;
        *(ushort4*)&Afull[1][lane][ct * 32 + wave * 4] = *(ushort4*)l;
    }
    xs[wave][lane] = x2loc;
    __syncthreads();

    // per-lane byte offset into a 32 KB slice (constant across ct)
    const unsigned vo = (unsigned)((quad * 512 + wave * 64 + lm) * 16);

    #pragma unroll 1
    for (int ct = 0; ct < 8; ++ct) {
        const __bf16* sb_hi = Bpack + (size_t)ct * 32768;
        const __bf16* sb_lo = sb_hi + 16384;

        // ---- issue all 8 B-loads (opaque asm defs: cannot be sunk) ----
        bf16x8 bh[4], bl[4];
        GLD(bh[0], vo, sb_hi, "0");
        GLD(bh[1], vo, sb_hi, "256");
        GLD(bh[2], vo, sb_hi, "512");
        GLD(bh[3], vo, sb_hi, "768");
        GLD(bl[0], vo, sb_lo, "0");
        GLD(bl[1], vo, sb_lo, "256");
        GLD(bl[2], vo, sb_lo, "512");
        GLD(bl[3], vo, sb_lo, "768");

        // ---- LDS A-reads overlap the B-load latency ----
        const int col = ct * 32 + quad * 8;
        bf16x8 a1[4];
        #pragma unroll
        for (int mt = 0; mt < 4; ++mt)
            a1[mt] = *(const bf16x8*)&Afull[0][mt * 16 + lm][col];

        asm volatile("s_waitcnt vmcnt(0)" ::: "memory");
        __builtin_amdgcn_sched_barrier(0);   // rule 18

        // SWAPPED operands: acc[mt][nt][r] =
        // C[spatial = mt*16+lm][code = wave*64 + nt*16 + quad*4 + r]
        #pragma unroll
        for (int nt = 0; nt < 4; ++nt)
            #pragma unroll
            for (int mt = 0; mt < 4; ++mt)
                acc[mt][nt] = __builtin_amdgcn_mfma_f32_16x16x32_bf16(bh[nt], a1[mt], acc[mt][nt], 0, 0, 0);
        #pragma unroll
        for (int nt = 0; nt < 4; ++nt)
            #pragma unroll
            for (int mt = 0; mt < 4; ++mt)
                acc[mt][nt] = __builtin_amdgcn_mfma_f32_16x16x32_bf16(bl[nt], a1[mt], acc[mt][nt], 0, 0, 0);
        #pragma unroll
        for (int mt = 0; mt < 4; ++mt) {
            bf16x8 a2 = *(const bf16x8*)&Afull[1][mt * 16 + lm][col];
            #pragma unroll
            for (int nt = 0; nt < 4; ++nt)
                acc[mt][nt] = __builtin_amdgcn_mfma_f32_16x16x32_bf16(bh[nt], a2, acc[mt][nt], 0, 0, 0);
        }
    }

    // ---- epilogue v5: per-thread top-2, zero cross-lane ops ----
    const int kbase = wave * 64;
    #pragma unroll
    for (int mt = 0; mt < 4; ++mt) {
        float v1 = __builtin_inff(), v2 = __builtin_inff();
        int k1 = 0x7fffffff, k2 = 0x7fffffff;
        #pragma unroll
        for (int nt = 0; nt < 4; ++nt) {
            float4 e4 = *(const float4*)&e2[kbase + nt * 16 + quad * 4];
            float ee[4] = {e4.x, e4.y, e4.z, e4.w};
            #pragma unroll
            for (int r = 0; r < 4; ++r) {
                float v = fmaf(-2.f, acc[mt][nt][r], ee[r]);
                ins2(v, kbase + nt * 16 + quad * 4 + r, v1, k1, v2, k2);
            }
        }
        stP(&cand[((size_t)((Mtile * 4 + mt) * 16 + lm)) * 32 + (wave * 4 + quad)],
            v1, k1, v2, k2);
    }

    // x2 (xs written before the prologue barrier -> visible)
    __syncthreads();
    if (tid < 64) {
        float xsum = 0.f;
        #pragma unroll
        for (int w = 0; w < 8; ++w) xsum += xs[w][tid];
        x2[Mtile * 64 + tid] = xsum;
    }
}

// ---------------- kernel 3: merge + refine + loss + DIRECT gather -------------
// R23 change: gather v3 — cb is 512 KB (fully L2-resident), so the LDS tile
// transpose + 8 barriers existed only to coalesce reads that are cache-hot
// anyway (Common-mistake #7). Direct per-thread writes: wave-coalesced 256B
// stores, lane-scattered L2-hot reads with 8-deep MLP. LDS 21->5 KB.
#define MARGIN 0.05f
__global__ void scatter_merge_kernel(const P2* __restrict__ cand,
                                     const float* __restrict__ x2arr,
                                     const float* __restrict__ pq,
                                     const float* __restrict__ cb,
                                     double* __restrict__ lossAcc,
                                     float* __restrict__ out) {
    int ntile = blockIdx.x, b = blockIdx.y, tid = threadIdx.x;
    int wave = tid >> 6, lane = tid & 63;
    __shared__ int idxs[64];
    __shared__ double dmin[64];
    __shared__ double lred[4];
    __shared__ __attribute__((aligned(16))) P2 m4[64][4];   // 4 KB partial merges
    __shared__ int trig_row[64], trig_s[64], trig_k1[64], trig_k2[64];
    __shared__ int ntrig;

    if (tid == 0) ntrig = 0;
    __syncthreads();

    // ---- phase 1a: 256 threads; each reads a CONTIGUOUS 128B chunk (8 recs) --
    {
        int rrow = tid >> 2, part = tid & 3;
        int Mtile2 = (b << 6) | rrow;
        int mt = (ntile >> 4) & 3, lmr = ntile & 15;
        const P2* cp = cand + ((size_t)((Mtile2 * 4 + mt) * 16 + lmr)) * 32;
        float v1 = __builtin_inff(), v2 = __builtin_inff();
        int k1 = 0x7fffffff, k2 = 0x7fffffff;
        #pragma unroll
        for (int j = 0; j < 8; ++j)
            insP(ldP(&cp[part * 8 + j]), v1, k1, v2, k2);
        stP(&m4[rrow][part], v1, k1, v2, k2);
    }
    __syncthreads();

    // ---- phase 1b: 64 threads finish (4-way) + trigger ----
    if (tid < 64) {
        int s = (tid << 6) | ntile;                     // sigma(p), p = ntile*64+tid
        int row = (b << 12) | s;
        float v1 = __builtin_inff(), v2 = __builtin_inff();
        int k1 = 0x7fffffff, k2 = 0x7fffffff;
        #pragma unroll
        for (int j = 0; j < 4; ++j)
            insP(ldP(&m4[tid][j]), v1, k1, v2, k2);

        idxs[tid] = k1;
        dmin[tid] = (double)(x2arr[row] + v1);
        if (v2 - v1 < MARGIN) {
            int i = atomicAdd(&ntrig, 1);
            trig_row[i] = tid; trig_s[i] = s;
            trig_k1[i] = k1; trig_k2[i] = k2;
        }
    }
    __syncthreads();

    int nt_ = ntrig;
    for (int i = wave; i < nt_; i += 4) {
        int s = trig_s[i], k1 = trig_k1[i], k2 = trig_k2[i];
        const float* xp  = pq + (size_t)b * (C_ * N_) + s;
        const float* ca  = cb + (size_t)k1 * C_;
        const float* cbp = cb + (size_t)k2 * C_;
        double da = 0.0, db = 0.0;
        #pragma unroll
        for (int j = 0; j < 4; ++j) {
            int c = j * 64 + lane;
            double xv = (double)xp[(size_t)c * N_];
            double ea = xv - (double)ca[c];  da += ea * ea;
            double eb = xv - (double)cbp[c]; db += eb * eb;
        }
        #pragma unroll
        for (int off = 32; off; off >>= 1) {
            da += __shfl_down(da, off);
            db += __shfl_down(db, off);
        }
        if (lane == 0) {
            int row = trig_row[i];
            if (db < da || (db == da && k2 < k1)) { idxs[row] = k2; dmin[row] = db; }
            else                                  { idxs[row] = k1; dmin[row] = da; }
        }
    }
    __syncthreads();

    double sd = (tid < 64) ? dmin[tid] : 0.0;
    #pragma unroll
    for (int off = 32; off; off >>= 1) sd += __shfl_down(sd, off);
    if ((tid & 63) == 0) lred[wave] = sd;
    __syncthreads();
    if (tid == 0) atomicAdd(lossAcc, lred[0] + lred[1] + lred[2] + lred[3]);

    // ---- gather v3: direct, no LDS transpose, no barriers ----
    {
        const float* cbrow = cb + (size_t)idxs[lane] * C_;
        float* outp = out + (size_t)b * (C_ * N_) + (size_t)ntile * 64 + lane;
        #pragma unroll 8
        for (int c = wave; c < C_; c += 4)
            outp[(size_t)c * N_] = cbrow[c];
    }
}

// ---------------- kernel 4: loss finalize ------------------------------------
__global__ void finalize_kernel(const double* __restrict__ lossAcc, float* __restrict__ out) {
    out[(size_t)B_ * C_ * N_] =
        (float)(1.25 * (*lossAcc) / (double)((size_t)B_ * N_ * C_));
}

// ---------------- launch ------------------------------------------------------
extern "C" void kernel_launch(void* const* d_in, const int* in_sizes, int n_in,
                              void* d_out, int out_size, void* d_ws, size_t ws_size,
                              hipStream_t stream) {
    const float* pq = (const float*)d_in[0];   // [16,256,64,64]
    const float* cb = (const float*)d_in[1];   // [512,256]
    float* out = (float*)d_out;                // 4194304 out + 1 loss
    char* ws = (char*)d_ws;
    double* lossAcc = (double*)ws;                            // 16 B
    float*  e2    = (float*)(ws + 16);                        // 2 KB
    float*  x2    = (float*)(ws + 16 + 2048);                 // 256 KB
    __bf16* Bpack = (__bf16*)(ws + 16 + 2048 + 262144);       // 512 KB
    P2* cand      = (P2*)(ws + 16 + 2048 + 262144 + 524288);  // 32 MB

    prep_kernel<<<K_, 64, 0, stream>>>(cb, e2, Bpack, lossAcc);
    main_kernel<<<1024, 512, 0, stream>>>(pq, Bpack, e2, cand, x2);
    scatter_merge_kernel<<<dim3(HW_, B_), 256, 0, stream>>>(cand, x2, pq, cb, lossAcc, out);
    finalize_kernel<<<1, 1, 0, stream>>>(lossAcc, out);
}

// Round 25
// 266.577 us; speedup vs baseline: 1.0834x; 1.0834x over previous
//
#include <hip/hip_runtime.h>
#include <cstdint>
#include <cstddef>

#define B_    16
#define C_    256
#define HW_   64
#define N_    4096      // 64*64 spatial
#define K_    512
#define NROW_ 65536     // B_*N_

typedef __attribute__((ext_vector_type(8))) __bf16 bf16x8;
typedef __attribute__((ext_vector_type(4))) float floatx4;

struct P2 { float v1; int k1; float v2; int k2; };

__device__ __forceinline__ bool lexless(float v, int k, float bv, int bk) {
    return (v < bv) || (v == bv && k < bk);
}
__device__ __forceinline__ void ins2(float v, int k, float& v1, int& k1, float& v2, int& k2) {
    if (lexless(v, k, v1, k1)) { v2 = v1; k2 = k1; v1 = v; k1 = k; }
    else if (lexless(v, k, v2, k2)) { v2 = v; k2 = k; }
}
// 16-B record moves (force b128 / dwordx4)
__device__ __forceinline__ P2 ldP(const P2* p) {
    uint4 u = *(const uint4*)p;
    P2 r; r.v1 = __uint_as_float(u.x); r.k1 = (int)u.y;
    r.v2 = __uint_as_float(u.z); r.k2 = (int)u.w; return r;
}
__device__ __forceinline__ void stP(P2* p, float v1, int k1, float v2, int k2) {
    uint4 u; u.x = __float_as_uint(v1); u.y = (unsigned)k1;
    u.z = __float_as_uint(v2); u.w = (unsigned)k2;
    *(uint4*)p = u;
}
__device__ __forceinline__ void insP(P2 p, float& v1, int& k1, float& v2, int& k2) {
    ins2(p.v1, p.k1, v1, k1, v2, k2);
    ins2(p.v2, p.k2, v1, k1, v2, k2);
}

// Bpack layout: [ct 8][plane 2][cq 4][n 512][i 8] bf16, 512 KB.
// cand layout (row-contiguous): [row_slot 65536][j 32] P2, 32 MB, where
//   row_slot = (Mtile*4 + mt)*16 + lm and j = wave*4 + quad.
//
// FINAL SESSION CONFIG (R21/R23, measured 266.9 / 272.2 us; baseline 370.9).
// Ledger (all REP-measured): main 144 = prologue 2 + K-loop 31 (MFMA-busy 21
// = 100% of dense-peak arithmetic for this problem) + epilogue ~15 + ~97
// structural latency residual (13 attribution experiments, no pipe
// saturated). scatter 110 = merge 26 + refine/loss/gather ~84 (LDS-transpose
// gather beats direct scattered reads by ~17 us — R24 measured).

// ---------------- kernel 1: codebook prep: e2 + packed bf16 hi/lo tiles -------
__global__ void prep_kernel(const float* __restrict__ cb, float* __restrict__ e2,
                            __bf16* __restrict__ Bpack, double* __restrict__ lossAcc) {
    int n = blockIdx.x, t = threadIdx.x;
    if (n == 0 && t == 0) *lossAcc = 0.0;
    float4 v = *(const float4*)(cb + (size_t)n * C_ + t * 4);
    float vv[4] = {v.x, v.y, v.z, v.w};
    __bf16 h[4], l[4];
    float s = 0.f;
    #pragma unroll
    for (int i = 0; i < 4; ++i) {
        h[i] = (__bf16)vv[i];
        l[i] = (__bf16)(vv[i] - (float)h[i]);
        s = fmaf(vv[i], vv[i], s);
    }
    int ct = t >> 3, cq = (t >> 1) & 3, i0 = (t & 1) * 4;
    size_t base = (size_t)ct * 32768;
    size_t off0 = base + ((size_t)(0 * 4 + cq) * 512 + n) * 8 + i0;   // hi plane
    size_t off1 = base + ((size_t)(1 * 4 + cq) * 512 + n) * 8 + i0;   // lo plane
    *(ushort4*)&Bpack[off0] = *(ushort4*)h;
    *(ushort4*)&Bpack[off1] = *(ushort4*)l;
    #pragma unroll
    for (int off = 32; off; off >>= 1) s += __shfl_down(s, off);
    if (t == 0) e2[n] = s;
}

// ---------------- kernel 2: SWAPPED-MFMA GEMM + per-thread top-2 --------------
#define GLD(dst, voff, sbase, OFF) \
    asm volatile("global_load_dwordx4 %0, %1, %2 offset:" OFF \
                 : "=v"(dst) : "v"(voff), "s"(sbase))

__launch_bounds__(512, 4)
__global__ void main_kernel(const float* __restrict__ pq,
                            const __bf16* __restrict__ Bpack,
                            const float* __restrict__ e2, P2* __restrict__ cand,
                            float* __restrict__ x2) {
    const int Mtile = blockIdx.x;
    const int tid  = threadIdx.x;
    const int wave = tid >> 6, lane = tid & 63;
    const int lm = lane & 15, quad = lane >> 4;
    const int b  = Mtile >> 6;
    const int s0 = (Mtile * 64) & 4095;

    __shared__ __attribute__((aligned(16))) __bf16 Afull[2][64][260]; // 66.5 KB
    __shared__ float  xs[8][64];                                      // 2 KB

    floatx4 acc[4][4];
    #pragma unroll
    for (int i = 0; i < 4; ++i)
        #pragma unroll
        for (int j = 0; j < 4; ++j) acc[i][j] = (floatx4)0.f;

    // ---- prologue: 32 independent coalesced pq loads (measured ~2 us) ----
    const float* pqA = pq + (size_t)b * (C_ * N_) + s0 + lane;
    float af[8][4];
    #pragma unroll
    for (int ct = 0; ct < 8; ++ct)
        #pragma unroll
        for (int i = 0; i < 4; ++i)
            af[ct][i] = pqA[(size_t)(ct * 32 + wave * 4 + i) * N_];

    float x2loc = 0.f;
    #pragma unroll
    for (int ct = 0; ct < 8; ++ct) {
        __bf16 h[4], l[4];
        #pragma unroll
        for (int i = 0; i < 4; ++i) {
            float a = af[ct][i];
            h[i] = (__bf16)a;
            l[i] = (__bf16)(a - (float)h[i]);
            x2loc = fmaf(a, a, x2loc);
        }
        *(ushort4*)&Afull[0][lane][ct * 32 + wave * 4] = *(ushort4*)h;
        *(ushort4*)&Afull[1][lane][ct * 32 + wave * 4] = *(ushort4*)l;
    }
    xs[wave][lane] = x2loc;
    __syncthreads();

    // per-lane byte offset into a 32 KB slice (constant across ct)
    const unsigned vo = (unsigned)((quad * 512 + wave * 64 + lm) * 16);

    #pragma unroll 1
    for (int ct = 0; ct < 8; ++ct) {
        const __bf16* sb_hi = Bpack + (size_t)ct * 32768;
        const __bf16* sb_lo = sb_hi + 16384;

        // ---- issue all 8 B-loads (opaque asm defs: cannot be sunk) ----
        bf16x8 bh[4], bl[4];
        GLD(bh[0], vo, sb_hi, "0");
        GLD(bh[1], vo, sb_hi, "256");
        GLD(bh[2], vo, sb_hi, "512");
        GLD(bh[3], vo, sb_hi, "768");
        GLD(bl[0], vo, sb_lo, "0");
        GLD(bl[1], vo, sb_lo, "256");
        GLD(bl[2], vo, sb_lo, "512");
        GLD(bl[3], vo, sb_lo, "768");

        // ---- LDS A-reads overlap the B-load latency ----
        const int col = ct * 32 + quad * 8;
        bf16x8 a1[4];
        #pragma unroll
        for (int mt = 0; mt < 4; ++mt)
            a1[mt] = *(const bf16x8*)&Afull[0][mt * 16 + lm][col];

        asm volatile("s_waitcnt vmcnt(0)" ::: "memory");
        __builtin_amdgcn_sched_barrier(0);   // rule 18

        // SWAPPED operands: acc[mt][nt][r] =
        // C[spatial = mt*16+lm][code = wave*64 + nt*16 + quad*4 + r]
        #pragma unroll
        for (int nt = 0; nt < 4; ++nt)
            #pragma unroll
            for (int mt = 0; mt < 4; ++mt)
                acc[mt][nt] = __builtin_amdgcn_mfma_f32_16x16x32_bf16(bh[nt], a1[mt], acc[mt][nt], 0, 0, 0);
        #pragma unroll
        for (int nt = 0; nt < 4; ++nt)
            #pragma unroll
            for (int mt = 0; mt < 4; ++mt)
                acc[mt][nt] = __builtin_amdgcn_mfma_f32_16x16x32_bf16(bl[nt], a1[mt], acc[mt][nt], 0, 0, 0);
        #pragma unroll
        for (int mt = 0; mt < 4; ++mt) {
            bf16x8 a2 = *(const bf16x8*)&Afull[1][mt * 16 + lm][col];
            #pragma unroll
            for (int nt = 0; nt < 4; ++nt)
                acc[mt][nt] = __builtin_amdgcn_mfma_f32_16x16x32_bf16(bh[nt], a2, acc[mt][nt], 0, 0, 0);
        }
    }

    // ---- epilogue v5: per-thread top-2, zero cross-lane ops ----
    const int kbase = wave * 64;
    #pragma unroll
    for (int mt = 0; mt < 4; ++mt) {
        float v1 = __builtin_inff(), v2 = __builtin_inff();
        int k1 = 0x7fffffff, k2 = 0x7fffffff;
        #pragma unroll
        for (int nt = 0; nt < 4; ++nt) {
            float4 e4 = *(const float4*)&e2[kbase + nt * 16 + quad * 4];
            float ee[4] = {e4.x, e4.y, e4.z, e4.w};
            #pragma unroll
            for (int r = 0; r < 4; ++r) {
                float v = fmaf(-2.f, acc[mt][nt][r], ee[r]);
                ins2(v, kbase + nt * 16 + quad * 4 + r, v1, k1, v2, k2);
            }
        }
        // row-contiguous store: row_slot=(Mtile*4+mt)*16+lm, j=wave*4+quad
        stP(&cand[((size_t)((Mtile * 4 + mt) * 16 + lm)) * 32 + (wave * 4 + quad)],
            v1, k1, v2, k2);
    }

    // x2 (xs written before the prologue barrier -> visible)
    __syncthreads();
    if (tid < 64) {
        float xsum = 0.f;
        #pragma unroll
        for (int w = 0; w < 8; ++w) xsum += xs[w][tid];
        x2[Mtile * 64 + tid] = xsum;
    }
}

// ---------------- kernel 3: merge(32-way, coalesced) + refine + loss + gather -
#define MARGIN 0.05f
__global__ void scatter_merge_kernel(const P2* __restrict__ cand,
                                     const float* __restrict__ x2arr,
                                     const float* __restrict__ pq,
                                     const float* __restrict__ cb,
                                     double* __restrict__ lossAcc,
                                     float* __restrict__ out) {
    int ntile = blockIdx.x, b = blockIdx.y, tid = threadIdx.x;
    int wave = tid >> 6, lane = tid & 63;
    __shared__ int idxs[64];
    __shared__ double dmin[64];
    __shared__ double lred[4];
    __shared__ float tile[64][65];
    __shared__ __attribute__((aligned(16))) P2 m4[64][4];   // 4 KB partial merges
    __shared__ int trig_row[64], trig_s[64], trig_k1[64], trig_k2[64];
    __shared__ int ntrig;

    if (tid == 0) ntrig = 0;
    __syncthreads();

    // ---- phase 1a: 256 threads; each reads a CONTIGUOUS 128B chunk (8 recs) --
    {
        int rrow = tid >> 2, part = tid & 3;
        int Mtile2 = (b << 6) | rrow;
        int mt = (ntile >> 4) & 3, lmr = ntile & 15;
        const P2* cp = cand + ((size_t)((Mtile2 * 4 + mt) * 16 + lmr)) * 32;
        float v1 = __builtin_inff(), v2 = __builtin_inff();
        int k1 = 0x7fffffff, k2 = 0x7fffffff;
        #pragma unroll
        for (int j = 0; j < 8; ++j)
            insP(ldP(&cp[part * 8 + j]), v1, k1, v2, k2);
        stP(&m4[rrow][part], v1, k1, v2, k2);
    }
    __syncthreads();

    // ---- phase 1b: 64 threads finish (4-way) + trigger ----
    if (tid < 64) {
        int s = (tid << 6) | ntile;                     // sigma(p), p = ntile*64+tid
        int row = (b << 12) | s;
        float v1 = __builtin_inff(), v2 = __builtin_inff();
        int k1 = 0x7fffffff, k2 = 0x7fffffff;
        #pragma unroll
        for (int j = 0; j < 4; ++j)
            insP(ldP(&m4[tid][j]), v1, k1, v2, k2);

        idxs[tid] = k1;
        dmin[tid] = (double)(x2arr[row] + v1);
        if (v2 - v1 < MARGIN) {
            int i = atomicAdd(&ntrig, 1);
            trig_row[i] = tid; trig_s[i] = s;
            trig_k1[i] = k1; trig_k2[i] = k2;
        }
    }
    __syncthreads();

    int nt_ = ntrig;
    for (int i = wave; i < nt_; i += 4) {
        int s = trig_s[i], k1 = trig_k1[i], k2 = trig_k2[i];
        const float* xp  = pq + (size_t)b * (C_ * N_) + s;
        const float* ca  = cb + (size_t)k1 * C_;
        const float* cbp = cb + (size_t)k2 * C_;
        double da = 0.0, db = 0.0;
        #pragma unroll
        for (int j = 0; j < 4; ++j) {
            int c = j * 64 + lane;
            double xv = (double)xp[(size_t)c * N_];
            double ea = xv - (double)ca[c];  da += ea * ea;
            double eb = xv - (double)cbp[c]; db += eb * eb;
        }
        #pragma unroll
        for (int off = 32; off; off >>= 1) {
            da += __shfl_down(da, off);
            db += __shfl_down(db, off);
        }
        if (lane == 0) {
            int row = trig_row[i];
            if (db < da || (db == da && k2 < k1)) { idxs[row] = k2; dmin[row] = db; }
            else                                  { idxs[row] = k1; dmin[row] = da; }
        }
    }
    __syncthreads();

    double sd = (tid < 64) ? dmin[tid] : 0.0;
    #pragma unroll
    for (int off = 32; off; off >>= 1) sd += __shfl_down(sd, off);
    if ((tid & 63) == 0) lred[wave] = sd;
    __syncthreads();
    if (tid == 0) atomicAdd(lossAcc, lred[0] + lred[1] + lred[2] + lred[3]);

    for (int cc = 0; cc < 4; ++cc) {
        int c0 = cc * 64;
        #pragma unroll
        for (int pp = 0; pp < 16; ++pp) {
            int i = pp * 4 + (tid >> 6);
            int c = tid & 63;
            tile[i][c] = cb[(size_t)idxs[i] * C_ + c0 + c];
        }
        __syncthreads();
        #pragma unroll
        for (int pp = 0; pp < 16; ++pp) {
            int cl = pp * 4 + (tid >> 6);
            int nl = tid & 63;
            out[((size_t)(b * C_ + c0 + cl)) * N_ + ntile * 64 + nl] = tile[nl][cl];
        }
        __syncthreads();
    }
}

// ---------------- kernel 4: loss finalize ------------------------------------
__global__ void finalize_kernel(const double* __restrict__ lossAcc, float* __restrict__ out) {
    out[(size_t)B_ * C_ * N_] =
        (float)(1.25 * (*lossAcc) / (double)((size_t)B_ * N_ * C_));
}

// ---------------- launch ------------------------------------------------------
extern "C" void kernel_launch(void* const* d_in, const int* in_sizes, int n_in,
                              void* d_out, int out_size, void* d_ws, size_t ws_size,
                              hipStream_t stream) {
    const float* pq = (const float*)d_in[0];   // [16,256,64,64]
    const float* cb = (const float*)d_in[1];   // [512,256]
    float* out = (float*)d_out;                // 4194304 out + 1 loss
    char* ws = (char*)d_ws;
    double* lossAcc = (double*)ws;                            // 16 B
    float*  e2    = (float*)(ws + 16);                        // 2 KB
    float*  x2    = (float*)(ws + 16 + 2048);                 // 256 KB
    __bf16* Bpack = (__bf16*)(ws + 16 + 2048 + 262144);       // 512 KB
    P2* cand      = (P2*)(ws + 16 + 2048 + 262144 + 524288);  // 32 MB

    prep_kernel<<<K_, 64, 0, stream>>>(cb, e2, Bpack, lossAcc);
    main_kernel<<<1024, 512, 0, stream>>>(pq, Bpack, e2, cand, x2);
    scatter_merge_kernel<<<dim3(HW_, B_), 256, 0, stream>>>(cand, x2, pq, cb, lossAcc, out);
    finalize_kernel<<<1, 1, 0, stream>>>(lossAcc, out);
}